// Round 16
// baseline (197.532 us; speedup 1.0000x reference)
//
#include <hip/hip_runtime.h>
#include <math.h>

#define BB 4096
#define TT 200
#define NT (BB*TT)

typedef __attribute__((ext_vector_type(8))) __bf16 bf16x8;
typedef __attribute__((ext_vector_type(4))) float f32x4;
typedef __attribute__((ext_vector_type(4))) _Float16 f16x4;

static __device__ __forceinline__ unsigned short f2b(float f) {
  __bf16 b = (__bf16)f;
  return __builtin_bit_cast(unsigned short, b);
}

// ---- prep: blocks <BB: TBuf[b][36] (parallel k-segments); >=BB: W1T ----
__global__ __launch_bounds__(256) void k_prep(
    const int* __restrict__ item, const float* __restrict__ Itab,
    const float* __restrict__ auW1, const float* __restrict__ auB1,
    const float* __restrict__ W1, float* __restrict__ TBuf,
    float* __restrict__ W1T) {
  const int blk = blockIdx.x, tid = threadIdx.x;
  if (blk >= BB) {
    int j = blk - BB;
    W1T[j * 256 + tid] = W1[tid * 80 + j];
    return;
  }
  __shared__ float sIe[64];
  __shared__ float sP[36][8];
  if (tid < 64) sIe[tid] = Itab[(size_t)item[blk] * 64 + tid];
  __syncthreads();
  if (tid < 252) {
    int j = tid / 7, s = tid - (tid / 7) * 7;
    const float* Wb_ = auW1 + 64 * 36;
    const float* Wc = auW1 + 128 * 36;
    int k0 = s * 10, k1 = (s == 6) ? 64 : (k0 + 10);
    float a = 0.f;
    for (int k = k0; k < k1; ++k)
      a = fmaf(sIe[k], Wb_[k * 36 + j] - Wc[k * 36 + j], a);
    sP[j][s] = a;
  }
  __syncthreads();
  if (tid < 36) {
    float a = auB1[tid];
#pragma unroll
    for (int s = 0; s < 7; ++s) a += sP[tid][s];
    TBuf[blk * 36 + tid] = a;
  }
}

// ---- K1: FULL-b GEMM [200(->208)x64]@[64x36]. 13-deep batched gather ->
// bf16 LDS; WBT in-kernel; MFMA; stats + coalesced X f16. 4 blocks/CU. ----
__global__ __launch_bounds__(256, 4) void k_gemm1(
    const int* __restrict__ hist, const int* __restrict__ item,
    const float* __restrict__ Itab, const float* __restrict__ auW1,
    const float* __restrict__ TBuf, float* __restrict__ PART,
    _Float16* __restrict__ Xb) {
  const int b = blockIdx.x, tid = threadIdx.x;
  const int wv = tid >> 6, l = tid & 63;
  const int lr = l & 15, lq = l >> 4;
  __shared__ __align__(16) unsigned short sHe[208 * 72];   // 29.9 KB
  __shared__ __align__(16) unsigned short sWBT[48 * 72];   // 6.9 KB
  __shared__ float sR1[192], sR2[192];

  const float ie_reg = Itab[(size_t)item[b] * 64 + l];

  // ---- batched staging: 13-deep. tasks i = tid + it*256 < 3200 ----
  const int* hp = hist + b * TT;
  int rowi[13];
#pragma unroll
  for (int it = 0; it < 13; ++it) {
    int i = tid + it * 256;
    int ic = i < 3200 ? i : 3199;
    rowi[it] = hp[ic >> 4];
  }
  float4 v[13];
#pragma unroll
  for (int it = 0; it < 13; ++it) {
    int i = tid + it * 256;
    int ic = i < 3200 ? i : 3199;
    v[it] = ((const float4*)(Itab + (size_t)rowi[it] * 64))[ic & 15];
  }
#pragma unroll
  for (int it = 0; it < 13; ++it) {
    int i = tid + it * 256;
    if (i < 3200) {
      ushort4 u;
      u.x = f2b(v[it].x); u.y = f2b(v[it].y);
      u.z = f2b(v[it].z); u.w = f2b(v[it].w);
      *(ushort4*)(sHe + (i >> 4) * 72 + (i & 15) * 4) = u;
    }
  }
  // zero pad rows 200..207
  for (int i = tid; i < 8 * 18; i += 256) {
    int r = TT + i / 18, c = i - (i / 18) * 18;
    *(ushort4*)(sHe + r * 72 + c * 4) = (ushort4){0, 0, 0, 0};
  }
  // build WBT[n][k] = Wa+Wc+ie[k]*Wd (bf16), overlaps gather
  {
    const float* Wc = auW1 + 128 * 36;
    const float* Wd = auW1 + 192 * 36;
#pragma unroll
    for (int it = 0; it < 12; ++it) {
      int i = tid + it * 256;
      int k = i / 48, n = i - (i / 48) * 48;
      float w = 0.f;
      if (n < 36) {
        int idx = k * 36 + n;
        float iek = __shfl(ie_reg, k, 64);
        w = (auW1[idx] + Wc[idx]) + iek * Wd[idx];
      }
      sWBT[n * 72 + k] = f2b(w);
    }
  }
  float tb3[3];
#pragma unroll
  for (int nt = 0; nt < 3; ++nt) {
    int j = nt * 16 + lr;
    tb3[nt] = (j < 36) ? TBuf[b * 36 + j] : 0.f;
  }
  __syncthreads();

  bf16x8 bfr[3][2];
#pragma unroll
  for (int nt = 0; nt < 3; ++nt)
#pragma unroll
    for (int kh = 0; kh < 2; ++kh)
      bfr[nt][kh] = *reinterpret_cast<const bf16x8*>(
          sWBT + (nt * 16 + lr) * 72 + kh * 32 + lq * 8);

  f32x4 acc[4][3];
#pragma unroll
  for (int mi = 0; mi < 4; ++mi)
#pragma unroll
    for (int nt = 0; nt < 3; ++nt) acc[mi][nt] = (f32x4){0.f, 0.f, 0.f, 0.f};

#pragma unroll
  for (int mi = 0; mi < 4; ++mi) {
    const int mt = wv + mi * 4;
    if (mt <= 12) {
      const unsigned short* ap = sHe + (mt * 16 + lr) * 72 + lq * 8;
      bf16x8 a0 = *reinterpret_cast<const bf16x8*>(ap);
      bf16x8 a1 = *reinterpret_cast<const bf16x8*>(ap + 32);
#pragma unroll
      for (int nt = 0; nt < 3; ++nt) {
        acc[mi][nt] = __builtin_amdgcn_mfma_f32_16x16x32_bf16(
            a0, bfr[nt][0], acc[mi][nt], 0, 0, 0);
        acc[mi][nt] = __builtin_amdgcn_mfma_f32_16x16x32_bf16(
            a1, bfr[nt][1], acc[mi][nt], 0, 0, 0);
      }
    }
  }

  // ---- all waves done reading sHe -> reuse it as f16 X staging ----
  __syncthreads();
  _Float16* sXs = (_Float16*)sHe;      // [200][36] f16 = 14.4 KB

  // stats + X->LDS. C map: t = mt*16 + lq*4 + q, j = nt*16 + lr
  float s1[3] = {0.f, 0.f, 0.f}, s2[3] = {0.f, 0.f, 0.f};
#pragma unroll
  for (int mi = 0; mi < 4; ++mi) {
    const int mt = wv + mi * 4;
    if (mt <= 12) {
#pragma unroll
      for (int q = 0; q < 4; ++q) {
        const int t = mt * 16 + lq * 4 + q;
        if (t < TT) {
#pragma unroll
          for (int nt = 0; nt < 3; ++nt) {
            const int j = nt * 16 + lr;
            float x = acc[mi][nt][q] + tb3[nt];
            if (j < 36) {
              s1[nt] += x;
              s2[nt] = fmaf(x, x, s2[nt]);
              sXs[t * 36 + j] = (_Float16)x;
            }
          }
        }
      }
    }
  }
#pragma unroll
  for (int nt = 0; nt < 3; ++nt) {
    float a = s1[nt], c = s2[nt];
    a += __shfl_xor(a, 16, 64); a += __shfl_xor(a, 32, 64);
    c += __shfl_xor(c, 16, 64); c += __shfl_xor(c, 32, 64);
    if (l < 16) {
      sR1[wv * 48 + nt * 16 + l] = a;
      sR2[wv * 48 + nt * 16 + l] = c;
    }
  }
  __syncthreads();
  if (tid < 36) {
    float a = sR1[tid] + sR1[48 + tid] + sR1[96 + tid] + sR1[144 + tid];
    float c = sR2[tid] + sR2[48 + tid] + sR2[96 + tid] + sR2[144 + tid];
    PART[b * 72 + tid] = a;
    PART[b * 72 + 36 + tid] = c;
  }
  // ---- coalesced X store: 7200 f16 = 900 uint4 ----
  {
    const uint4* src = (const uint4*)sXs;
    uint4* dst = (uint4*)(Xb + (size_t)b * 7200);
#pragma unroll
    for (int it = 0; it < 4; ++it) {
      int i = tid + it * 256;
      if (i < 900) dst[i] = src[i];
    }
  }
}

// ---- AU stats finalize over 4096 partials ----
__global__ __launch_bounds__(256) void k_aust(const float* __restrict__ PART,
                                              float* __restrict__ AUST) {
  int ch = blockIdx.x, tid = threadIdx.x;  // grid 36
  float s1 = 0.f, s2 = 0.f;
  for (int blk = tid; blk < BB; blk += 256) {
    s1 += PART[blk * 72 + ch];
    s2 += PART[blk * 72 + 36 + ch];
  }
  __shared__ float r1[256], r2[256];
  r1[tid] = s1;
  r2[tid] = s2;
  __syncthreads();
  for (int off = 128; off > 0; off >>= 1) {
    if (tid < off) { r1[tid] += r1[tid + off]; r2[tid] += r2[tid + off]; }
    __syncthreads();
  }
  if (tid == 0) {
    float m = r1[0] / (float)NT;
    float var = r2[0] / (float)NT - m * m;
    AUST[ch] = m;
    AUST[36 + ch] = 1.0f / sqrtf(var + 1e-8f);
  }
}

// ---- K2: read X (f16x4), dice+w, ILP-4 pool, concat, parallel MLP1 ----
__global__ __launch_bounds__(256) void k_att(
    const int* __restrict__ hist, const int* __restrict__ user,
    const int* __restrict__ item, const int* __restrict__ cate,
    const float* __restrict__ Itab, const float* __restrict__ Utab,
    const float* __restrict__ Ctab, const _Float16* __restrict__ Xb,
    const float* __restrict__ AUST, const float* __restrict__ auA1,
    const float* __restrict__ auW2, const float* __restrict__ auB2,
    const float* __restrict__ W1T, const float* __restrict__ b1,
    float* __restrict__ Y1) {
  const int b = blockIdx.x, tid = threadIdx.x;
  __shared__ float sW[TT];
  __shared__ int sRows[TT];
  __shared__ float sD[144];
  __shared__ float sPart[256];
  __shared__ float sX[256];
  __shared__ float sMp[160];
  if (tid < TT) sRows[tid] = hist[b * TT + tid];
  if (tid >= 208 && tid < 208 + 36) sD[tid - 208] = AUST[tid - 208];
  else if (tid < 36) sD[36 + tid] = AUST[36 + tid];
  else if (tid >= 64 && tid < 100) sD[72 + (tid - 64)] = auA1[tid - 64];
  else if (tid >= 128 && tid < 164) sD[108 + (tid - 128)] = auW2[tid - 128];
  __syncthreads();
  if (tid < TT) {
    const f16x4* xr = (const f16x4*)(Xb + (size_t)b * 7200 + tid * 36);
    float w = auB2[0];
#pragma unroll
    for (int p = 0; p < 9; ++p) {
      f16x4 pr = xr[p];
#pragma unroll
      for (int h = 0; h < 4; ++h) {
        int j = 4 * p + h;
        float x = (float)pr[h];
        float xh = (x - sD[j]) * sD[36 + j];
        float pp = 1.0f / (1.0f + __expf(-xh));
        float al = sD[72 + j];
        w = fmaf(x * (al + pp * (1.0f - al)), sD[108 + j], w);
      }
    }
    sW[tid] = w;
  }
  __syncthreads();
  {
    const int l = tid & 63, wv = tid >> 6;
    const int t0 = wv * 50;
    float c0 = 0.f, c1 = 0.f, c2 = 0.f, c3 = 0.f;
#pragma unroll
    for (int g = 0; g < 12; ++g) {
      int u = t0 + g * 4;
      c0 = fmaf(sW[u + 0], Itab[(size_t)sRows[u + 0] * 64 + l], c0);
      c1 = fmaf(sW[u + 1], Itab[(size_t)sRows[u + 1] * 64 + l], c1);
      c2 = fmaf(sW[u + 2], Itab[(size_t)sRows[u + 2] * 64 + l], c2);
      c3 = fmaf(sW[u + 3], Itab[(size_t)sRows[u + 3] * 64 + l], c3);
    }
    c0 = fmaf(sW[t0 + 48], Itab[(size_t)sRows[t0 + 48] * 64 + l], c0);
    c1 = fmaf(sW[t0 + 49], Itab[(size_t)sRows[t0 + 49] * 64 + l], c1);
    sPart[tid] = (c0 + c1) + (c2 + c3);
  }
  __syncthreads();
  if (tid < 64) {
    float cur = sPart[tid] + sPart[64 + tid] + sPart[128 + tid] + sPart[192 + tid];
    sX[tid] = Utab[(size_t)user[b] * 64 + tid];
    sX[64 + tid] = Itab[(size_t)item[b] * 64 + tid];
    sX[128 + tid] = Ctab[(size_t)cate[b] * 64 + tid];
    sX[192 + tid] = cur;
  }
  __syncthreads();
  // MLP1: 160 threads = 2 per output j (k-halves), ILP-4 accumulators
  if (tid < 160) {
    const int j = (tid < 80) ? tid : (tid - 80);
    const int h = (tid < 80) ? 0 : 1;
    const float4* wt = (const float4*)(W1T + j * 256 + h * 128);
    const float* xs = sX + h * 128;
    float a0 = 0.f, a1 = 0.f, a2 = 0.f, a3 = 0.f;
#pragma unroll 8
    for (int kq = 0; kq < 32; ++kq) {
      float4 w4 = wt[kq];
      a0 = fmaf(xs[kq * 4 + 0], w4.x, a0);
      a1 = fmaf(xs[kq * 4 + 1], w4.y, a1);
      a2 = fmaf(xs[kq * 4 + 2], w4.z, a2);
      a3 = fmaf(xs[kq * 4 + 3], w4.w, a3);
    }
    sMp[h * 80 + j] = (a0 + a1) + (a2 + a3);
  }
  __syncthreads();
  if (tid < 80) Y1[b * 80 + tid] = b1[tid] + sMp[tid] + sMp[80 + tid];
}

// ---- per-channel batch stats over [B, nch] ----
__global__ __launch_bounds__(256) void k_colstats(const float* __restrict__ src,
                                                  int nch, float* __restrict__ st) {
  int ch = blockIdx.x, tid = threadIdx.x;
  float s1 = 0.f, s2 = 0.f;
  for (int r = tid; r < BB; r += 256) {
    float v = src[r * nch + ch];
    s1 += v;
    s2 += v * v;
  }
  __shared__ float r1[256], r2[256];
  r1[tid] = s1;
  r2[tid] = s2;
  __syncthreads();
  for (int off = 128; off > 0; off >>= 1) {
    if (tid < off) { r1[tid] += r1[tid + off]; r2[tid] += r2[tid + off]; }
    __syncthreads();
  }
  if (tid == 0) {
    float m = r1[0] / (float)BB;
    float var = r2[0] / (float)BB - m * m;
    st[ch] = m;
    st[nch + ch] = 1.0f / sqrtf(var + 1e-8f);
  }
}

// ---- MLP layer 2 ----
__global__ __launch_bounds__(128) void k_mlp2(const float* __restrict__ Y1,
                                              const float* __restrict__ ST80,
                                              const float* __restrict__ a1,
                                              const float* __restrict__ W2,
                                              const float* __restrict__ b2,
                                              float* __restrict__ Y2) {
  int b = blockIdx.x, tid = threadIdx.x;
  __shared__ float sY[80];
  if (tid < 80) {
    float x = Y1[b * 80 + tid];
    float xh = (x - ST80[tid]) * ST80[80 + tid];
    float p = 1.0f / (1.0f + expf(-xh));
    sY[tid] = p * x + (1.0f - p) * a1[tid] * x;
  }
  __syncthreads();
  if (tid < 40) {
    float a0 = b2[tid], a1_ = 0.f;
    for (int k = 0; k < 80; k += 2) {
      a0 = fmaf(sY[k], W2[k * 40 + tid], a0);
      a1_ = fmaf(sY[k + 1], W2[(k + 1) * 40 + tid], a1_);
    }
    Y2[b * 40 + tid] = a0 + a1_;
  }
}

// ---- MLP layer 3 ----
__global__ __launch_bounds__(64) void k_mlp3(const float* __restrict__ Y2,
                                             const float* __restrict__ ST40,
                                             const float* __restrict__ a2,
                                             const float* __restrict__ W3,
                                             const float* __restrict__ b3,
                                             float* __restrict__ out) {
  int b = blockIdx.x, tid = threadIdx.x;
  __shared__ float sY[40];
  if (tid < 40) {
    float x = Y2[b * 40 + tid];
    float xh = (x - ST40[tid]) * ST40[40 + tid];
    float p = 1.0f / (1.0f + expf(-xh));
    sY[tid] = p * x + (1.0f - p) * a2[tid] * x;
  }
  __syncthreads();
  if (tid < 2) {
    float a0 = b3[tid], a1_ = 0.f;
    for (int k = 0; k < 40; k += 2) {
      a0 = fmaf(sY[k], W3[k * 2 + tid], a0);
      a1_ = fmaf(sY[k + 1], W3[(k + 1) * 2 + tid], a1_);
    }
    out[b * 2 + tid] = a0 + a1_;
  }
}

extern "C" void kernel_launch(void* const* d_in, const int* in_sizes, int n_in,
                              void* d_out, int out_size, void* d_ws, size_t ws_size,
                              hipStream_t stream) {
  const int* user = (const int*)d_in[0];
  const int* hist = (const int*)d_in[1];
  const int* item = (const int*)d_in[2];
  const int* cate = (const int*)d_in[3];
  const float* Utab = (const float*)d_in[4];
  const float* Itab = (const float*)d_in[5];
  const float* Ctab = (const float*)d_in[6];
  const float* auW1 = (const float*)d_in[7];
  const float* auB1 = (const float*)d_in[8];
  const float* auA1 = (const float*)d_in[9];
  const float* auW2 = (const float*)d_in[10];
  const float* auB2 = (const float*)d_in[11];
  const float* W1 = (const float*)d_in[12];
  const float* b1 = (const float*)d_in[13];
  const float* a1 = (const float*)d_in[14];
  const float* W2 = (const float*)d_in[15];
  const float* b2 = (const float*)d_in[16];
  const float* a2 = (const float*)d_in[17];
  const float* W3 = (const float*)d_in[18];
  const float* b3 = (const float*)d_in[19];
  float* out = (float*)d_out;

  float* ws = (float*)d_ws;
  float* TBuf = ws;                        // BB*36
  float* PART = TBuf + BB * 36;            // BB*72
  float* AUST = PART + BB * 72;            // 72
  float* Y1 = AUST + 72;                   // BB*80
  float* ST80 = Y1 + BB * 80;              // 160
  float* Y2 = ST80 + 160;                  // BB*40
  float* ST40 = Y2 + BB * 40;              // 80
  float* W1T = ST40 + 80;                  // 80*256
  _Float16* Xb = (_Float16*)(W1T + 80 * 256);  // BB*7200 f16 (59 MB)

  k_prep<<<BB + 80, 256, 0, stream>>>(item, Itab, auW1, auB1, W1, TBuf, W1T);
  k_gemm1<<<BB, 256, 0, stream>>>(hist, item, Itab, auW1, TBuf, PART, Xb);
  k_aust<<<36, 256, 0, stream>>>(PART, AUST);
  k_att<<<BB, 256, 0, stream>>>(hist, user, item, cate, Itab, Utab, Ctab, Xb,
                                AUST, auA1, auW2, auB2, W1T, b1, Y1);
  k_colstats<<<80, 256, 0, stream>>>(Y1, 80, ST80);
  k_mlp2<<<BB, 128, 0, stream>>>(Y1, ST80, a1, W2, b2, Y2);
  k_colstats<<<40, 256, 0, stream>>>(Y2, 40, ST40);
  k_mlp3<<<BB, 64, 0, stream>>>(Y2, ST40, a2, W3, b3, out);
}

// Round 17
// 196.094 us; speedup vs baseline: 1.0073x; 1.0073x over previous
//
#include <hip/hip_runtime.h>
#include <math.h>

#define BB 4096
#define TT 200
#define NT (BB*TT)

typedef __attribute__((ext_vector_type(8))) __bf16 bf16x8;
typedef __attribute__((ext_vector_type(4))) float f32x4;
typedef __attribute__((ext_vector_type(4))) _Float16 f16x4;

static __device__ __forceinline__ unsigned short f2b(float f) {
  __bf16 b = (__bf16)f;
  return __builtin_bit_cast(unsigned short, b);
}

// ---- prep: blocks <BB: TBuf[b][36] (parallel k-segments); >=BB: W1T ----
__global__ __launch_bounds__(256) void k_prep(
    const int* __restrict__ item, const float* __restrict__ Itab,
    const float* __restrict__ auW1, const float* __restrict__ auB1,
    const float* __restrict__ W1, float* __restrict__ TBuf,
    float* __restrict__ W1T) {
  const int blk = blockIdx.x, tid = threadIdx.x;
  if (blk >= BB) {
    int j = blk - BB;
    W1T[j * 256 + tid] = W1[tid * 80 + j];
    return;
  }
  __shared__ float sIe[64];
  __shared__ float sP[36][8];
  if (tid < 64) sIe[tid] = Itab[(size_t)item[blk] * 64 + tid];
  __syncthreads();
  if (tid < 252) {
    int j = tid / 7, s = tid - (tid / 7) * 7;
    const float* Wb_ = auW1 + 64 * 36;
    const float* Wc = auW1 + 128 * 36;
    int k0 = s * 10, k1 = (s == 6) ? 64 : (k0 + 10);
    float a = 0.f;
    for (int k = k0; k < k1; ++k)
      a = fmaf(sIe[k], Wb_[k * 36 + j] - Wc[k * 36 + j], a);
    sP[j][s] = a;
  }
  __syncthreads();
  if (tid < 36) {
    float a = auB1[tid];
#pragma unroll
    for (int s = 0; s < 7; ++s) a += sP[tid][s];
    TBuf[blk * 36 + tid] = a;
  }
}

// ---- K1: FULL-b GEMM [200(->208)x64]@[64x36]. 13-deep batched gather ->
// bf16 LDS; WBT in-kernel; MFMA; stats + coalesced X f16. (256,3). ----
__global__ __launch_bounds__(256, 3) void k_gemm1(
    const int* __restrict__ hist, const int* __restrict__ item,
    const float* __restrict__ Itab, const float* __restrict__ auW1,
    const float* __restrict__ TBuf, float* __restrict__ PART,
    _Float16* __restrict__ Xb) {
  const int b = blockIdx.x, tid = threadIdx.x;
  const int wv = tid >> 6, l = tid & 63;
  const int lr = l & 15, lq = l >> 4;
  __shared__ __align__(16) unsigned short sHe[208 * 72];   // 29.9 KB
  __shared__ __align__(16) unsigned short sWBT[48 * 72];   // 6.9 KB
  __shared__ float sR1[192], sR2[192];

  const float ie_reg = Itab[(size_t)item[b] * 64 + l];

  // ---- batched staging: 13-deep. tasks i = tid + it*256 < 3200 ----
  const int* hp = hist + b * TT;
  int rowi[13];
#pragma unroll
  for (int it = 0; it < 13; ++it) {
    int i = tid + it * 256;
    int ic = i < 3200 ? i : 3199;
    rowi[it] = hp[ic >> 4];
  }
  float4 v[13];
#pragma unroll
  for (int it = 0; it < 13; ++it) {
    int i = tid + it * 256;
    int ic = i < 3200 ? i : 3199;
    v[it] = ((const float4*)(Itab + (size_t)rowi[it] * 64))[ic & 15];
  }
#pragma unroll
  for (int it = 0; it < 13; ++it) {
    int i = tid + it * 256;
    if (i < 3200) {
      ushort4 u;
      u.x = f2b(v[it].x); u.y = f2b(v[it].y);
      u.z = f2b(v[it].z); u.w = f2b(v[it].w);
      *(ushort4*)(sHe + (i >> 4) * 72 + (i & 15) * 4) = u;
    }
  }
  // zero pad rows 200..207
  for (int i = tid; i < 8 * 18; i += 256) {
    int r = TT + i / 18, c = i - (i / 18) * 18;
    *(ushort4*)(sHe + r * 72 + c * 4) = (ushort4){0, 0, 0, 0};
  }
  // build WBT[n][k] = Wa+Wc+ie[k]*Wd (bf16), overlaps gather
  {
    const float* Wc = auW1 + 128 * 36;
    const float* Wd = auW1 + 192 * 36;
#pragma unroll
    for (int it = 0; it < 12; ++it) {
      int i = tid + it * 256;
      int k = i / 48, n = i - (i / 48) * 48;
      float w = 0.f;
      if (n < 36) {
        int idx = k * 36 + n;
        float iek = __shfl(ie_reg, k, 64);
        w = (auW1[idx] + Wc[idx]) + iek * Wd[idx];
      }
      sWBT[n * 72 + k] = f2b(w);
    }
  }
  float tb3[3];
#pragma unroll
  for (int nt = 0; nt < 3; ++nt) {
    int j = nt * 16 + lr;
    tb3[nt] = (j < 36) ? TBuf[b * 36 + j] : 0.f;
  }
  __syncthreads();

  bf16x8 bfr[3][2];
#pragma unroll
  for (int nt = 0; nt < 3; ++nt)
#pragma unroll
    for (int kh = 0; kh < 2; ++kh)
      bfr[nt][kh] = *reinterpret_cast<const bf16x8*>(
          sWBT + (nt * 16 + lr) * 72 + kh * 32 + lq * 8);

  f32x4 acc[4][3];
#pragma unroll
  for (int mi = 0; mi < 4; ++mi)
#pragma unroll
    for (int nt = 0; nt < 3; ++nt) acc[mi][nt] = (f32x4){0.f, 0.f, 0.f, 0.f};

#pragma unroll
  for (int mi = 0; mi < 4; ++mi) {
    const int mt = wv + mi * 4;
    if (mt <= 12) {
      const unsigned short* ap = sHe + (mt * 16 + lr) * 72 + lq * 8;
      bf16x8 a0 = *reinterpret_cast<const bf16x8*>(ap);
      bf16x8 a1 = *reinterpret_cast<const bf16x8*>(ap + 32);
#pragma unroll
      for (int nt = 0; nt < 3; ++nt) {
        acc[mi][nt] = __builtin_amdgcn_mfma_f32_16x16x32_bf16(
            a0, bfr[nt][0], acc[mi][nt], 0, 0, 0);
        acc[mi][nt] = __builtin_amdgcn_mfma_f32_16x16x32_bf16(
            a1, bfr[nt][1], acc[mi][nt], 0, 0, 0);
      }
    }
  }

  // ---- all waves done reading sHe -> reuse it as f16 X staging ----
  __syncthreads();
  _Float16* sXs = (_Float16*)sHe;      // [200][36] f16 = 14.4 KB

  // stats + X->LDS. C map: t = mt*16 + lq*4 + q, j = nt*16 + lr
  float s1[3] = {0.f, 0.f, 0.f}, s2[3] = {0.f, 0.f, 0.f};
#pragma unroll
  for (int mi = 0; mi < 4; ++mi) {
    const int mt = wv + mi * 4;
    if (mt <= 12) {
#pragma unroll
      for (int q = 0; q < 4; ++q) {
        const int t = mt * 16 + lq * 4 + q;
        if (t < TT) {
#pragma unroll
          for (int nt = 0; nt < 3; ++nt) {
            const int j = nt * 16 + lr;
            float x = acc[mi][nt][q] + tb3[nt];
            if (j < 36) {
              s1[nt] += x;
              s2[nt] = fmaf(x, x, s2[nt]);
              sXs[t * 36 + j] = (_Float16)x;
            }
          }
        }
      }
    }
  }
#pragma unroll
  for (int nt = 0; nt < 3; ++nt) {
    float a = s1[nt], c = s2[nt];
    a += __shfl_xor(a, 16, 64); a += __shfl_xor(a, 32, 64);
    c += __shfl_xor(c, 16, 64); c += __shfl_xor(c, 32, 64);
    if (l < 16) {
      sR1[wv * 48 + nt * 16 + l] = a;
      sR2[wv * 48 + nt * 16 + l] = c;
    }
  }
  __syncthreads();
  if (tid < 36) {
    float a = sR1[tid] + sR1[48 + tid] + sR1[96 + tid] + sR1[144 + tid];
    float c = sR2[tid] + sR2[48 + tid] + sR2[96 + tid] + sR2[144 + tid];
    PART[b * 72 + tid] = a;
    PART[b * 72 + 36 + tid] = c;
  }
  // ---- coalesced X store: 7200 f16 = 900 uint4 ----
  {
    const uint4* src = (const uint4*)sXs;
    uint4* dst = (uint4*)(Xb + (size_t)b * 7200);
#pragma unroll
    for (int it = 0; it < 4; ++it) {
      int i = tid + it * 256;
      if (i < 900) dst[i] = src[i];
    }
  }
}

// ---- AU stats finalize over 4096 partials ----
__global__ __launch_bounds__(256) void k_aust(const float* __restrict__ PART,
                                              float* __restrict__ AUST) {
  int ch = blockIdx.x, tid = threadIdx.x;  // grid 36
  float s1 = 0.f, s2 = 0.f;
  for (int blk = tid; blk < BB; blk += 256) {
    s1 += PART[blk * 72 + ch];
    s2 += PART[blk * 72 + 36 + ch];
  }
  __shared__ float r1[256], r2[256];
  r1[tid] = s1;
  r2[tid] = s2;
  __syncthreads();
  for (int off = 128; off > 0; off >>= 1) {
    if (tid < off) { r1[tid] += r1[tid + off]; r2[tid] += r2[tid + off]; }
    __syncthreads();
  }
  if (tid == 0) {
    float m = r1[0] / (float)NT;
    float var = r2[0] / (float)NT - m * m;
    AUST[ch] = m;
    AUST[36 + ch] = 1.0f / sqrtf(var + 1e-8f);
  }
}

// ---- K2: read X (f16x4), dice+w, ILP-4 pool, concat, parallel MLP1 ----
__global__ __launch_bounds__(256) void k_att(
    const int* __restrict__ hist, const int* __restrict__ user,
    const int* __restrict__ item, const int* __restrict__ cate,
    const float* __restrict__ Itab, const float* __restrict__ Utab,
    const float* __restrict__ Ctab, const _Float16* __restrict__ Xb,
    const float* __restrict__ AUST, const float* __restrict__ auA1,
    const float* __restrict__ auW2, const float* __restrict__ auB2,
    const float* __restrict__ W1T, const float* __restrict__ b1,
    float* __restrict__ Y1) {
  const int b = blockIdx.x, tid = threadIdx.x;
  __shared__ float sW[TT];
  __shared__ int sRows[TT];
  __shared__ float sD[144];
  __shared__ float sPart[256];
  __shared__ float sX[256];
  __shared__ float sMp[160];
  if (tid < TT) sRows[tid] = hist[b * TT + tid];
  if (tid >= 208 && tid < 208 + 36) sD[tid - 208] = AUST[tid - 208];
  else if (tid < 36) sD[36 + tid] = AUST[36 + tid];
  else if (tid >= 64 && tid < 100) sD[72 + (tid - 64)] = auA1[tid - 64];
  else if (tid >= 128 && tid < 164) sD[108 + (tid - 128)] = auW2[tid - 128];
  __syncthreads();
  if (tid < TT) {
    const f16x4* xr = (const f16x4*)(Xb + (size_t)b * 7200 + tid * 36);
    float w = auB2[0];
#pragma unroll
    for (int p = 0; p < 9; ++p) {
      f16x4 pr = xr[p];
#pragma unroll
      for (int h = 0; h < 4; ++h) {
        int j = 4 * p + h;
        float x = (float)pr[h];
        float xh = (x - sD[j]) * sD[36 + j];
        float pp = 1.0f / (1.0f + __expf(-xh));
        float al = sD[72 + j];
        w = fmaf(x * (al + pp * (1.0f - al)), sD[108 + j], w);
      }
    }
    sW[tid] = w;
  }
  __syncthreads();
  {
    const int l = tid & 63, wv = tid >> 6;
    const int t0 = wv * 50;
    float c0 = 0.f, c1 = 0.f, c2 = 0.f, c3 = 0.f;
#pragma unroll
    for (int g = 0; g < 12; ++g) {
      int u = t0 + g * 4;
      c0 = fmaf(sW[u + 0], Itab[(size_t)sRows[u + 0] * 64 + l], c0);
      c1 = fmaf(sW[u + 1], Itab[(size_t)sRows[u + 1] * 64 + l], c1);
      c2 = fmaf(sW[u + 2], Itab[(size_t)sRows[u + 2] * 64 + l], c2);
      c3 = fmaf(sW[u + 3], Itab[(size_t)sRows[u + 3] * 64 + l], c3);
    }
    c0 = fmaf(sW[t0 + 48], Itab[(size_t)sRows[t0 + 48] * 64 + l], c0);
    c1 = fmaf(sW[t0 + 49], Itab[(size_t)sRows[t0 + 49] * 64 + l], c1);
    sPart[tid] = (c0 + c1) + (c2 + c3);
  }
  __syncthreads();
  if (tid < 64) {
    float cur = sPart[tid] + sPart[64 + tid] + sPart[128 + tid] + sPart[192 + tid];
    sX[tid] = Utab[(size_t)user[b] * 64 + tid];
    sX[64 + tid] = Itab[(size_t)item[b] * 64 + tid];
    sX[128 + tid] = Ctab[(size_t)cate[b] * 64 + tid];
    sX[192 + tid] = cur;
  }
  __syncthreads();
  // MLP1: 160 threads = 2 per output j (k-halves), ILP-4 accumulators
  if (tid < 160) {
    const int j = (tid < 80) ? tid : (tid - 80);
    const int h = (tid < 80) ? 0 : 1;
    const float4* wt = (const float4*)(W1T + j * 256 + h * 128);
    const float* xs = sX + h * 128;
    float a0 = 0.f, a1 = 0.f, a2 = 0.f, a3 = 0.f;
#pragma unroll 8
    for (int kq = 0; kq < 32; ++kq) {
      float4 w4 = wt[kq];
      a0 = fmaf(xs[kq * 4 + 0], w4.x, a0);
      a1 = fmaf(xs[kq * 4 + 1], w4.y, a1);
      a2 = fmaf(xs[kq * 4 + 2], w4.z, a2);
      a3 = fmaf(xs[kq * 4 + 3], w4.w, a3);
    }
    sMp[h * 80 + j] = (a0 + a1) + (a2 + a3);
  }
  __syncthreads();
  if (tid < 80) Y1[b * 80 + tid] = b1[tid] + sMp[tid] + sMp[80 + tid];
}

// ---- per-channel batch stats over [B, nch] ----
__global__ __launch_bounds__(256) void k_colstats(const float* __restrict__ src,
                                                  int nch, float* __restrict__ st) {
  int ch = blockIdx.x, tid = threadIdx.x;
  float s1 = 0.f, s2 = 0.f;
  for (int r = tid; r < BB; r += 256) {
    float v = src[r * nch + ch];
    s1 += v;
    s2 += v * v;
  }
  __shared__ float r1[256], r2[256];
  r1[tid] = s1;
  r2[tid] = s2;
  __syncthreads();
  for (int off = 128; off > 0; off >>= 1) {
    if (tid < off) { r1[tid] += r1[tid + off]; r2[tid] += r2[tid + off]; }
    __syncthreads();
  }
  if (tid == 0) {
    float m = r1[0] / (float)BB;
    float var = r2[0] / (float)BB - m * m;
    st[ch] = m;
    st[nch + ch] = 1.0f / sqrtf(var + 1e-8f);
  }
}

// ---- MLP layer 2 ----
__global__ __launch_bounds__(128) void k_mlp2(const float* __restrict__ Y1,
                                              const float* __restrict__ ST80,
                                              const float* __restrict__ a1,
                                              const float* __restrict__ W2,
                                              const float* __restrict__ b2,
                                              float* __restrict__ Y2) {
  int b = blockIdx.x, tid = threadIdx.x;
  __shared__ float sY[80];
  if (tid < 80) {
    float x = Y1[b * 80 + tid];
    float xh = (x - ST80[tid]) * ST80[80 + tid];
    float p = 1.0f / (1.0f + expf(-xh));
    sY[tid] = p * x + (1.0f - p) * a1[tid] * x;
  }
  __syncthreads();
  if (tid < 40) {
    float a0 = b2[tid], a1_ = 0.f;
    for (int k = 0; k < 80; k += 2) {
      a0 = fmaf(sY[k], W2[k * 40 + tid], a0);
      a1_ = fmaf(sY[k + 1], W2[(k + 1) * 40 + tid], a1_);
    }
    Y2[b * 40 + tid] = a0 + a1_;
  }
}

// ---- MLP layer 3 ----
__global__ __launch_bounds__(64) void k_mlp3(const float* __restrict__ Y2,
                                             const float* __restrict__ ST40,
                                             const float* __restrict__ a2,
                                             const float* __restrict__ W3,
                                             const float* __restrict__ b3,
                                             float* __restrict__ out) {
  int b = blockIdx.x, tid = threadIdx.x;
  __shared__ float sY[40];
  if (tid < 40) {
    float x = Y2[b * 40 + tid];
    float xh = (x - ST40[tid]) * ST40[40 + tid];
    float p = 1.0f / (1.0f + expf(-xh));
    sY[tid] = p * x + (1.0f - p) * a2[tid] * x;
  }
  __syncthreads();
  if (tid < 2) {
    float a0 = b3[tid], a1_ = 0.f;
    for (int k = 0; k < 40; k += 2) {
      a0 = fmaf(sY[k], W3[k * 2 + tid], a0);
      a1_ = fmaf(sY[k + 1], W3[(k + 1) * 2 + tid], a1_);
    }
    out[b * 2 + tid] = a0 + a1_;
  }
}

extern "C" void kernel_launch(void* const* d_in, const int* in_sizes, int n_in,
                              void* d_out, int out_size, void* d_ws, size_t ws_size,
                              hipStream_t stream) {
  const int* user = (const int*)d_in[0];
  const int* hist = (const int*)d_in[1];
  const int* item = (const int*)d_in[2];
  const int* cate = (const int*)d_in[3];
  const float* Utab = (const float*)d_in[4];
  const float* Itab = (const float*)d_in[5];
  const float* Ctab = (const float*)d_in[6];
  const float* auW1 = (const float*)d_in[7];
  const float* auB1 = (const float*)d_in[8];
  const float* auA1 = (const float*)d_in[9];
  const float* auW2 = (const float*)d_in[10];
  const float* auB2 = (const float*)d_in[11];
  const float* W1 = (const float*)d_in[12];
  const float* b1 = (const float*)d_in[13];
  const float* a1 = (const float*)d_in[14];
  const float* W2 = (const float*)d_in[15];
  const float* b2 = (const float*)d_in[16];
  const float* a2 = (const float*)d_in[17];
  const float* W3 = (const float*)d_in[18];
  const float* b3 = (const float*)d_in[19];
  float* out = (float*)d_out;

  float* ws = (float*)d_ws;
  float* TBuf = ws;                        // BB*36
  float* PART = TBuf + BB * 36;            // BB*72
  float* AUST = PART + BB * 72;            // 72
  float* Y1 = AUST + 72;                   // BB*80
  float* ST80 = Y1 + BB * 80;              // 160
  float* Y2 = ST80 + 160;                  // BB*40
  float* ST40 = Y2 + BB * 40;              // 80
  float* W1T = ST40 + 80;                  // 80*256
  _Float16* Xb = (_Float16*)(W1T + 80 * 256);  // BB*7200 f16 (59 MB)

  k_prep<<<BB + 80, 256, 0, stream>>>(item, Itab, auW1, auB1, W1, TBuf, W1T);
  k_gemm1<<<BB, 256, 0, stream>>>(hist, item, Itab, auW1, TBuf, PART, Xb);
  k_aust<<<36, 256, 0, stream>>>(PART, AUST);
  k_att<<<BB, 256, 0, stream>>>(hist, user, item, cate, Itab, Utab, Ctab, Xb,
                                AUST, auA1, auW2, auB2, W1T, b1, Y1);
  k_colstats<<<80, 256, 0, stream>>>(Y1, 80, ST80);
  k_mlp2<<<BB, 128, 0, stream>>>(Y1, ST80, a1, W2, b2, Y2);
  k_colstats<<<40, 256, 0, stream>>>(Y2, 40, ST40);
  k_mlp3<<<BB, 64, 0, stream>>>(Y2, ST40, a2, W3, b3, out);
}

// Round 18
// 178.181 us; speedup vs baseline: 1.1086x; 1.1005x over previous
//
#include <hip/hip_runtime.h>
#include <math.h>

#define BB 4096
#define TT 200
#define NT (BB*TT)

typedef __attribute__((ext_vector_type(8))) __bf16 bf16x8;
typedef __attribute__((ext_vector_type(4))) float f32x4;
typedef __attribute__((ext_vector_type(4))) _Float16 f16x4;

static __device__ __forceinline__ unsigned short f2b(float f) {
  __bf16 b = (__bf16)f;
  return __builtin_bit_cast(unsigned short, b);
}

// ---- prep: blocks <BB: TBuf[b][36]; blocks >=BB: W1T (80 rows) ----
__global__ __launch_bounds__(256) void k_prep(
    const int* __restrict__ item, const float* __restrict__ Itab,
    const float* __restrict__ auW1, const float* __restrict__ auB1,
    const float* __restrict__ W1, float* __restrict__ TBuf,
    float* __restrict__ W1T) {
  const int blk = blockIdx.x, tid = threadIdx.x;
  if (blk >= BB) {
    int j = blk - BB;
    W1T[j * 256 + tid] = W1[tid * 80 + j];
    return;
  }
  __shared__ float sIe[64];
  if (tid < 64) sIe[tid] = Itab[(size_t)item[blk] * 64 + tid];
  __syncthreads();
  if (tid < 36) {
    const float* Wb_ = auW1 + 64 * 36;
    const float* Wc = auW1 + 128 * 36;
    float a = auB1[tid];
    for (int k = 0; k < 64; ++k)
      a += sIe[k] * (Wb_[k * 36 + tid] - Wc[k * 36 + tid]);
    TBuf[blk * 36 + tid] = a;
  }
}

// ---- K1: FULL-b GEMM [200(->208)x64]@[64x36]. 13-deep batched gather ->
// bf16 LDS; WBT in-kernel (once per b); MFMA; stats + coalesced X f16. ----
__global__ __launch_bounds__(256, 3) void k_gemm1(
    const int* __restrict__ hist, const int* __restrict__ item,
    const float* __restrict__ Itab, const float* __restrict__ auW1,
    const float* __restrict__ TBuf, float* __restrict__ PART,
    _Float16* __restrict__ Xb) {
  const int b = blockIdx.x, tid = threadIdx.x;
  const int wv = tid >> 6, l = tid & 63;
  const int lr = l & 15, lq = l >> 4;
  __shared__ __align__(16) unsigned short sHe[208 * 72];   // 29.9 KB
  __shared__ __align__(16) unsigned short sWBT[48 * 72];   // 6.9 KB
  __shared__ float sR1[192], sR2[192];

  const float ie_reg = Itab[(size_t)item[b] * 64 + l];

  // ---- batched staging: 13-deep. tasks i = tid + it*256 < 3200 ----
  const int* hp = hist + b * TT;
  int rowi[13];
#pragma unroll
  for (int it = 0; it < 13; ++it) {
    int i = tid + it * 256;
    int ic = i < 3200 ? i : 3199;
    rowi[it] = hp[ic >> 4];             // independent index loads
  }
  float4 v[13];
#pragma unroll
  for (int it = 0; it < 13; ++it) {
    int i = tid + it * 256;
    int ic = i < 3200 ? i : 3199;
    v[it] = ((const float4*)(Itab + (size_t)rowi[it] * 64))[ic & 15];
  }
#pragma unroll
  for (int it = 0; it < 13; ++it) {
    int i = tid + it * 256;
    if (i < 3200) {
      ushort4 u;
      u.x = f2b(v[it].x); u.y = f2b(v[it].y);
      u.z = f2b(v[it].z); u.w = f2b(v[it].w);
      *(ushort4*)(sHe + (i >> 4) * 72 + (i & 15) * 4) = u;
    }
  }
  // zero pad rows 200..207
  for (int i = tid; i < 8 * 18; i += 256) {
    int r = TT + i / 18, c = i - (i / 18) * 18;
    *(ushort4*)(sHe + r * 72 + c * 4) = (ushort4){0, 0, 0, 0};
  }
  // build WBT[n][k] = Wa+Wc+ie[k]*Wd (bf16), overlaps gather
  {
    const float* Wc = auW1 + 128 * 36;
    const float* Wd = auW1 + 192 * 36;
#pragma unroll
    for (int it = 0; it < 12; ++it) {
      int i = tid + it * 256;
      int k = i / 48, n = i - (i / 48) * 48;
      float w = 0.f;
      if (n < 36) {
        int idx = k * 36 + n;
        float iek = __shfl(ie_reg, k, 64);
        w = (auW1[idx] + Wc[idx]) + iek * Wd[idx];
      }
      sWBT[n * 72 + k] = f2b(w);
    }
  }
  float tb3[3];
#pragma unroll
  for (int nt = 0; nt < 3; ++nt) {
    int j = nt * 16 + lr;
    tb3[nt] = (j < 36) ? TBuf[b * 36 + j] : 0.f;
  }
  __syncthreads();

  bf16x8 bfr[3][2];
#pragma unroll
  for (int nt = 0; nt < 3; ++nt)
#pragma unroll
    for (int kh = 0; kh < 2; ++kh)
      bfr[nt][kh] = *reinterpret_cast<const bf16x8*>(
          sWBT + (nt * 16 + lr) * 72 + kh * 32 + lq * 8);

  f32x4 acc[4][3];
#pragma unroll
  for (int mi = 0; mi < 4; ++mi)
#pragma unroll
    for (int nt = 0; nt < 3; ++nt) acc[mi][nt] = (f32x4){0.f, 0.f, 0.f, 0.f};

#pragma unroll
  for (int mi = 0; mi < 4; ++mi) {
    const int mt = wv + mi * 4;
    if (mt <= 12) {
      const unsigned short* ap = sHe + (mt * 16 + lr) * 72 + lq * 8;
      bf16x8 a0 = *reinterpret_cast<const bf16x8*>(ap);
      bf16x8 a1 = *reinterpret_cast<const bf16x8*>(ap + 32);
#pragma unroll
      for (int nt = 0; nt < 3; ++nt) {
        acc[mi][nt] = __builtin_amdgcn_mfma_f32_16x16x32_bf16(
            a0, bfr[nt][0], acc[mi][nt], 0, 0, 0);
        acc[mi][nt] = __builtin_amdgcn_mfma_f32_16x16x32_bf16(
            a1, bfr[nt][1], acc[mi][nt], 0, 0, 0);
      }
    }
  }

  // ---- all waves done reading sHe -> reuse it as f16 X staging ----
  __syncthreads();
  _Float16* sXs = (_Float16*)sHe;      // [200][36] f16 = 14.4 KB

  // stats + X->LDS. C map: t = mt*16 + lq*4 + q, j = nt*16 + lr
  float s1[3] = {0.f, 0.f, 0.f}, s2[3] = {0.f, 0.f, 0.f};
#pragma unroll
  for (int mi = 0; mi < 4; ++mi) {
    const int mt = wv + mi * 4;
    if (mt <= 12) {
#pragma unroll
      for (int q = 0; q < 4; ++q) {
        const int t = mt * 16 + lq * 4 + q;
        if (t < TT) {
#pragma unroll
          for (int nt = 0; nt < 3; ++nt) {
            const int j = nt * 16 + lr;
            float x = acc[mi][nt][q] + tb3[nt];
            if (j < 36) {
              s1[nt] += x;
              s2[nt] = fmaf(x, x, s2[nt]);
              sXs[t * 36 + j] = (_Float16)x;
            }
          }
        }
      }
    }
  }
#pragma unroll
  for (int nt = 0; nt < 3; ++nt) {
    float a = s1[nt], c = s2[nt];
    a += __shfl_xor(a, 16, 64); a += __shfl_xor(a, 32, 64);
    c += __shfl_xor(c, 16, 64); c += __shfl_xor(c, 32, 64);
    if (l < 16) {
      sR1[wv * 48 + nt * 16 + l] = a;
      sR2[wv * 48 + nt * 16 + l] = c;
    }
  }
  __syncthreads();
  if (tid < 36) {
    float a = sR1[tid] + sR1[48 + tid] + sR1[96 + tid] + sR1[144 + tid];
    float c = sR2[tid] + sR2[48 + tid] + sR2[96 + tid] + sR2[144 + tid];
    PART[b * 72 + tid] = a;
    PART[b * 72 + 36 + tid] = c;
  }
  // ---- coalesced X store: 7200 f16 = 900 uint4 ----
  {
    const uint4* src = (const uint4*)sXs;
    uint4* dst = (uint4*)(Xb + (size_t)b * 7200);
#pragma unroll
    for (int it = 0; it < 4; ++it) {
      int i = tid + it * 256;
      if (i < 900) dst[i] = src[i];
    }
  }
}

// ---- AU stats finalize over 4096 partials ----
__global__ __launch_bounds__(256) void k_aust(const float* __restrict__ PART,
                                              float* __restrict__ AUST) {
  int ch = blockIdx.x, tid = threadIdx.x;  // grid 36
  float s1 = 0.f, s2 = 0.f;
  for (int blk = tid; blk < BB; blk += 256) {
    s1 += PART[blk * 72 + ch];
    s2 += PART[blk * 72 + 36 + ch];
  }
  __shared__ float r1[256], r2[256];
  r1[tid] = s1;
  r2[tid] = s2;
  __syncthreads();
  for (int off = 128; off > 0; off >>= 1) {
    if (tid < off) { r1[tid] += r1[tid + off]; r2[tid] += r2[tid + off]; }
    __syncthreads();
  }
  if (tid == 0) {
    float m = r1[0] / (float)NT;
    float var = r2[0] / (float)NT - m * m;
    AUST[ch] = m;
    AUST[36 + ch] = 1.0f / sqrtf(var + 1e-8f);
  }
}

// ---- K2: read X (f16x4), dice+w, ILP-4 pool, concat, MLP1 ----
__global__ __launch_bounds__(256) void k_att(
    const int* __restrict__ hist, const int* __restrict__ user,
    const int* __restrict__ item, const int* __restrict__ cate,
    const float* __restrict__ Itab, const float* __restrict__ Utab,
    const float* __restrict__ Ctab, const _Float16* __restrict__ Xb,
    const float* __restrict__ AUST, const float* __restrict__ auA1,
    const float* __restrict__ auW2, const float* __restrict__ auB2,
    const float* __restrict__ W1T, const float* __restrict__ b1,
    float* __restrict__ Y1) {
  const int b = blockIdx.x, tid = threadIdx.x;
  __shared__ float sW[TT];
  __shared__ int sRows[TT];
  __shared__ float sD[144];
  __shared__ float sPart[256];
  __shared__ float sX[256];
  if (tid < TT) sRows[tid] = hist[b * TT + tid];
  if (tid >= 208 && tid < 208 + 36) sD[tid - 208] = AUST[tid - 208];
  else if (tid < 36) sD[36 + tid] = AUST[36 + tid];
  else if (tid >= 64 && tid < 100) sD[72 + (tid - 64)] = auA1[tid - 64];
  else if (tid >= 128 && tid < 164) sD[108 + (tid - 128)] = auW2[tid - 128];
  __syncthreads();
  if (tid < TT) {
    const f16x4* xr = (const f16x4*)(Xb + (size_t)b * 7200 + tid * 36);
    float w = auB2[0];
#pragma unroll
    for (int p = 0; p < 9; ++p) {
      f16x4 pr = xr[p];
#pragma unroll
      for (int h = 0; h < 4; ++h) {
        int j = 4 * p + h;
        float x = (float)pr[h];
        float xh = (x - sD[j]) * sD[36 + j];
        float pp = 1.0f / (1.0f + __expf(-xh));
        float al = sD[72 + j];
        w = fmaf(x * (al + pp * (1.0f - al)), sD[108 + j], w);
      }
    }
    sW[tid] = w;
  }
  __syncthreads();
  {
    const int l = tid & 63, wv = tid >> 6;
    const int t0 = wv * 50;
    float c0 = 0.f, c1 = 0.f, c2 = 0.f, c3 = 0.f;
#pragma unroll
    for (int g = 0; g < 12; ++g) {
      int u = t0 + g * 4;
      c0 = fmaf(sW[u + 0], Itab[(size_t)sRows[u + 0] * 64 + l], c0);
      c1 = fmaf(sW[u + 1], Itab[(size_t)sRows[u + 1] * 64 + l], c1);
      c2 = fmaf(sW[u + 2], Itab[(size_t)sRows[u + 2] * 64 + l], c2);
      c3 = fmaf(sW[u + 3], Itab[(size_t)sRows[u + 3] * 64 + l], c3);
    }
    c0 = fmaf(sW[t0 + 48], Itab[(size_t)sRows[t0 + 48] * 64 + l], c0);
    c1 = fmaf(sW[t0 + 49], Itab[(size_t)sRows[t0 + 49] * 64 + l], c1);
    sPart[tid] = (c0 + c1) + (c2 + c3);
  }
  __syncthreads();
  if (tid < 64) {
    float cur = sPart[tid] + sPart[64 + tid] + sPart[128 + tid] + sPart[192 + tid];
    sX[tid] = Utab[(size_t)user[b] * 64 + tid];
    sX[64 + tid] = Itab[(size_t)item[b] * 64 + tid];
    sX[128 + tid] = Ctab[(size_t)cate[b] * 64 + tid];
    sX[192 + tid] = cur;
  }
  __syncthreads();
  if (tid < 80) {
    float a = b1[tid];
    const float4* wt = (const float4*)(W1T + tid * 256);
#pragma unroll 8
    for (int kq = 0; kq < 64; ++kq) {
      float4 w4 = wt[kq];
      a = fmaf(sX[kq * 4 + 0], w4.x, a);
      a = fmaf(sX[kq * 4 + 1], w4.y, a);
      a = fmaf(sX[kq * 4 + 2], w4.z, a);
      a = fmaf(sX[kq * 4 + 3], w4.w, a);
    }
    Y1[b * 80 + tid] = a;
  }
}

// ---- per-channel batch stats over [B, nch] ----
__global__ __launch_bounds__(256) void k_colstats(const float* __restrict__ src,
                                                  int nch, float* __restrict__ st) {
  int ch = blockIdx.x, tid = threadIdx.x;
  float s1 = 0.f, s2 = 0.f;
  for (int r = tid; r < BB; r += 256) {
    float v = src[r * nch + ch];
    s1 += v;
    s2 += v * v;
  }
  __shared__ float r1[256], r2[256];
  r1[tid] = s1;
  r2[tid] = s2;
  __syncthreads();
  for (int off = 128; off > 0; off >>= 1) {
    if (tid < off) { r1[tid] += r1[tid + off]; r2[tid] += r2[tid + off]; }
    __syncthreads();
  }
  if (tid == 0) {
    float m = r1[0] / (float)BB;
    float var = r2[0] / (float)BB - m * m;
    st[ch] = m;
    st[nch + ch] = 1.0f / sqrtf(var + 1e-8f);
  }
}

// ---- MLP layer 2 ----
__global__ __launch_bounds__(128) void k_mlp2(const float* __restrict__ Y1,
                                              const float* __restrict__ ST80,
                                              const float* __restrict__ a1,
                                              const float* __restrict__ W2,
                                              const float* __restrict__ b2,
                                              float* __restrict__ Y2) {
  int b = blockIdx.x, tid = threadIdx.x;
  __shared__ float sY[80];
  if (tid < 80) {
    float x = Y1[b * 80 + tid];
    float xh = (x - ST80[tid]) * ST80[80 + tid];
    float p = 1.0f / (1.0f + expf(-xh));
    sY[tid] = p * x + (1.0f - p) * a1[tid] * x;
  }
  __syncthreads();
  if (tid < 40) {
    float a = b2[tid];
    for (int k = 0; k < 80; ++k) a += sY[k] * W2[k * 40 + tid];
    Y2[b * 40 + tid] = a;
  }
}

// ---- MLP layer 3 ----
__global__ __launch_bounds__(64) void k_mlp3(const float* __restrict__ Y2,
                                             const float* __restrict__ ST40,
                                             const float* __restrict__ a2,
                                             const float* __restrict__ W3,
                                             const float* __restrict__ b3,
                                             float* __restrict__ out) {
  int b = blockIdx.x, tid = threadIdx.x;
  __shared__ float sY[40];
  if (tid < 40) {
    float x = Y2[b * 40 + tid];
    float xh = (x - ST40[tid]) * ST40[40 + tid];
    float p = 1.0f / (1.0f + expf(-xh));
    sY[tid] = p * x + (1.0f - p) * a2[tid] * x;
  }
  __syncthreads();
  if (tid < 2) {
    float a = b3[tid];
    for (int k = 0; k < 40; ++k) a += sY[k] * W3[k * 2 + tid];
    out[b * 2 + tid] = a;
  }
}

extern "C" void kernel_launch(void* const* d_in, const int* in_sizes, int n_in,
                              void* d_out, int out_size, void* d_ws, size_t ws_size,
                              hipStream_t stream) {
  const int* user = (const int*)d_in[0];
  const int* hist = (const int*)d_in[1];
  const int* item = (const int*)d_in[2];
  const int* cate = (const int*)d_in[3];
  const float* Utab = (const float*)d_in[4];
  const float* Itab = (const float*)d_in[5];
  const float* Ctab = (const float*)d_in[6];
  const float* auW1 = (const float*)d_in[7];
  const float* auB1 = (const float*)d_in[8];
  const float* auA1 = (const float*)d_in[9];
  const float* auW2 = (const float*)d_in[10];
  const float* auB2 = (const float*)d_in[11];
  const float* W1 = (const float*)d_in[12];
  const float* b1 = (const float*)d_in[13];
  const float* a1 = (const float*)d_in[14];
  const float* W2 = (const float*)d_in[15];
  const float* b2 = (const float*)d_in[16];
  const float* a2 = (const float*)d_in[17];
  const float* W3 = (const float*)d_in[18];
  const float* b3 = (const float*)d_in[19];
  float* out = (float*)d_out;

  float* ws = (float*)d_ws;
  float* TBuf = ws;                        // BB*36
  float* PART = TBuf + BB * 36;            // BB*72
  float* AUST = PART + BB * 72;            // 72
  float* Y1 = AUST + 72;                   // BB*80
  float* ST80 = Y1 + BB * 80;              // 160
  float* Y2 = ST80 + 160;                  // BB*40
  float* ST40 = Y2 + BB * 40;              // 80
  float* W1T = ST40 + 80;                  // 80*256
  _Float16* Xb = (_Float16*)(W1T + 80 * 256);  // BB*7200 f16 (59 MB)

  k_prep<<<BB + 80, 256, 0, stream>>>(item, Itab, auW1, auB1, W1, TBuf, W1T);
  k_gemm1<<<BB, 256, 0, stream>>>(hist, item, Itab, auW1, TBuf, PART, Xb);
  k_aust<<<36, 256, 0, stream>>>(PART, AUST);
  k_att<<<BB, 256, 0, stream>>>(hist, user, item, cate, Itab, Utab, Ctab, Xb,
                                AUST, auA1, auW2, auB2, W1T, b1, Y1);
  k_colstats<<<80, 256, 0, stream>>>(Y1, 80, ST80);
  k_mlp2<<<BB, 128, 0, stream>>>(Y1, ST80, a1, W2, b2, Y2);
  k_colstats<<<40, 256, 0, stream>>>(Y2, 40, ST40);
  k_mlp3<<<BB, 64, 0, stream>>>(Y2, ST40, a2, W3, b3, out);
}